// Round 8
// baseline (85.992 us; speedup 1.0000x reference)
//
#include <hip/hip_runtime.h>
#include <math.h>

#define BATCH   4
#define NPTS    8192
#define THREADS 256
#define CHUNK   1024                  // targets staged per LDS chunk
#define NCHUNKS (NPTS / CHUNK)        // 8
#define NBLOCKS (2 * BATCH * (NPTS / 128))   // 512: (dir, b, 128-query group)

typedef _Float16 h8   __attribute__((ext_vector_type(8)));   // 4 VGPRs
typedef float    f16v __attribute__((ext_vector_type(16)));  // 16 VGPRs

// ---------------------------------------------------------------------------
// Fused kernel. One block = (dir, batch, 128 queries); each of 4 waves owns a
// 32-query tile vs all 8192 targets via split-f16 mfma_f32_32x32x16_f16
// (math verified r6: D = tt - 2 q~.t~, omitted ql.tl ~2e-5 << threshold).
//  - targets transformed in-block while staging to LDS (no separate pass)
//  - DIRECT LDS slots + consecutive-record ds_read_b128 (r6's proven
//    pattern; consecutive 16B reads across lanes are full-rate)
//  - plain fminf merge (r7's inline-asm v_min3 consuming MFMA results is
//    the prime suspect for the non-deterministic r7 failure: opaque asm
//    readers of MFMA dests sidestep the compiler's hazard wait-states)
//  - epilogue: butterfly-min over 32 cols, add |q|^2 (f32, stashed in LDS),
//    clamp, sqrt, block-sum -> bsum[bid]
// ---------------------------------------------------------------------------
__global__ __launch_bounds__(THREADS, 2)
void chamfer_fused_kernel(const float* __restrict__ pred,
                          const float* __restrict__ target,
                          float* __restrict__ bsum)
{
    __shared__ uint4 slo[CHUNK];   // 16 KB  (k-slots 0..7  of B records)
    __shared__ uint4 shi[CHUNK];   // 16 KB  (k-slots 8..15 of B records)
    __shared__ float sqq[128];     // |q|^2 per block-query
    __shared__ float wsum[8];

    const int tid  = threadIdx.x;
    const int lane = tid & 63;
    const int wave = tid >> 6;
    const int n    = lane & 31;
    const int hi   = lane >> 5;

    const int bid = blockIdx.x;
    const int qg  = bid & 63;
    const int b   = (bid >> 6) & 3;
    const int dir = bid >> 8;        // 0: q=pred, db=target ; 1: swapped

    const float* qraw = ((dir == 0) ? pred : target) + (size_t)b * NPTS * 3;
    const float* draw = ((dir == 0) ? target : pred) + (size_t)b * NPTS * 3;

    const int qtbase = qg * 128 + wave * 32;

    // ---- A fragment (split-f16 query) + |q|^2 stash ----
    h8 afrag;
    {
        const float* qp = qraw + (size_t)(qtbase + n) * 3;
        const float x = qp[0], y = qp[1], z = qp[2];
        const _Float16 hx = (_Float16)x; const _Float16 lx = (_Float16)(x - (float)hx);
        const _Float16 hy = (_Float16)y; const _Float16 ly = (_Float16)(y - (float)hy);
        const _Float16 hz = (_Float16)z; const _Float16 lz = (_Float16)(z - (float)hz);
        const _Float16 one  = (_Float16)1.0f;
        const _Float16 zero = (_Float16)0.0f;
        if (hi == 0) {
            afrag = (h8){hx, hy, hz, one, lx, ly, lz, one};
            sqq[wave * 32 + n] = fmaf(x, x, fmaf(y, y, z * z));
        } else {
            afrag = (h8){hx, hy, hz, zero, zero, zero, zero, zero};
        }
    }

    float mn[16];
    #pragma unroll
    for (int i = 0; i < 16; ++i) mn[i] = 3.0e38f;

    const float4* dra4 = (const float4*)draw;           // 16B-aligned
    const uint4*  bsrc = hi ? shi : slo;

    for (int c = 0; c < NCHUNKS; ++c) {
        // ---- stage + transform 4 target points per thread (direct slots) ----
        {
            const int base4 = c * 768 + 3 * tid;        // float4 index
            const float4 f0 = dra4[base4 + 0];
            const float4 f1 = dra4[base4 + 1];
            const float4 f2 = dra4[base4 + 2];
            const float px[4] = {f0.x, f0.w, f1.z, f2.y};
            const float py[4] = {f0.y, f1.x, f1.w, f2.z};
            const float pz[4] = {f0.z, f1.y, f2.x, f2.w};

            #pragma unroll
            for (int k = 0; k < 4; ++k) {
                const float x = px[k], y = py[k], z = pz[k];
                const _Float16 hx = (_Float16)x; const _Float16 lx = (_Float16)(x - (float)hx);
                const _Float16 hy = (_Float16)y; const _Float16 ly = (_Float16)(y - (float)hy);
                const _Float16 hz = (_Float16)z; const _Float16 lz = (_Float16)(z - (float)hz);
                const float tx = (float)hx + (float)lx;
                const float ty = (float)hy + (float)ly;
                const float tz = (float)hz + (float)lz;
                const float tt = fmaf(tx, tx, fmaf(ty, ty, tz * tz));
                const _Float16 tth = (_Float16)tt;
                const _Float16 ttl = (_Float16)(tt - (float)tth);
                const _Float16 n2 = (_Float16)(-2.0f);
                const _Float16 zz = (_Float16)0.0f;
                h8 lo = { n2 * hx, n2 * hy, n2 * hz, tth,
                          n2 * hx, n2 * hy, n2 * hz, ttl };
                h8 hh = { n2 * lx, n2 * ly, n2 * lz, zz, zz, zz, zz, zz };
                const int slot = 4 * tid + k;           // DIRECT (no swizzle)
                slo[slot] = *(const uint4*)&lo;
                shi[slot] = *(const uint4*)&hh;
            }
        }
        __syncthreads();

        // ---- 32 MFMA tiles (r6's proven loop shape) ----
        #pragma unroll 2
        for (int t = 0; t < CHUNK / 32; ++t) {
            const h8 bfrag = *(const h8*)&bsrc[t * 32 + n];
            const f16v zc = {};
            const f16v d = __builtin_amdgcn_mfma_f32_32x32x16_f16(afrag, bfrag, zc, 0, 0, 0);
            #pragma unroll
            for (int i = 0; i < 16; ++i)
                mn[i] = fminf(mn[i], d[i]);
        }
        __syncthreads();
    }

    // ---- butterfly min over the 32 columns (stays within each 32-half) ----
    #pragma unroll
    for (int mask = 1; mask <= 16; mask <<= 1) {
        #pragma unroll
        for (int i = 0; i < 16; ++i)
            mn[i] = fminf(mn[i], __shfl_xor(mn[i], mask, 64));
    }

    // ---- epilogue: qq + clamp + sqrt + partial sum ----
    if (n == 0) {
        float s = 0.0f;
        #pragma unroll
        for (int i = 0; i < 16; ++i) {
            const int row = (i & 3) + 8 * (i >> 2) + 4 * hi;
            s += sqrtf(fmaxf(sqq[wave * 32 + row] + mn[i], 1e-12f));
        }
        wsum[wave * 2 + hi] = s;
    }
    __syncthreads();
    if (tid == 0) {
        float t = 0.0f;
        #pragma unroll
        for (int k = 0; k < 8; ++k) t += wsum[k];
        bsum[bid] = t;
    }
}

// final: sum 512 block sums, write mean over batches
__global__ __launch_bounds__(THREADS)
void chamfer_final(const float* __restrict__ bsum,
                   float* __restrict__ out)
{
    const int tid = threadIdx.x;
    float v = bsum[tid] + bsum[tid + 256];
    #pragma unroll
    for (int off = 32; off > 0; off >>= 1)
        v += __shfl_down(v, off, 64);

    __shared__ float wsum[4];
    if ((tid & 63) == 0) wsum[tid >> 6] = v;
    __syncthreads();
    if (tid == 0) out[0] = (wsum[0] + wsum[1] + wsum[2] + wsum[3]) * (1.0f / BATCH);
}

extern "C" void kernel_launch(void* const* d_in, const int* in_sizes, int n_in,
                              void* d_out, int out_size, void* d_ws, size_t ws_size,
                              hipStream_t stream)
{
    const float* pred   = (const float*)d_in[0];
    const float* target = (const float*)d_in[1];
    float* out          = (float*)d_out;
    float* bsum         = (float*)d_ws;    // 512 floats

    chamfer_fused_kernel<<<NBLOCKS, THREADS, 0, stream>>>(pred, target, bsum);
    chamfer_final<<<1, THREADS, 0, stream>>>(bsum, out);
}